// Round 1
// baseline (6500.903 us; speedup 1.0000x reference)
//
#include <hip/hip_runtime.h>
#include <cstdint>
#include <cstddef>

#define T_LEN 16384
#define R_CH  128
#define BATCH 8
#define NLAYER 9

__device__ __forceinline__ float fast_sigmoid(float x) {
    return 1.0f / (1.0f + __expf(-x));
}
__device__ __forceinline__ float fast_tanh(float x) {
    // tanh(x) = 1 - 2/(exp(2x)+1); correct limits at +-inf
    return 1.0f - 2.0f / (__expf(2.0f * x) + 1.0f);
}

// ---------------------------------------------------------------------------
// Weight pre-transpose:
//  wA[l][kk][c]  (kk = tap*128 + r, c in [0,256))  = conv_w[l][c][r][tap]
//  wB[l][k][c2]: c2<128 -> out_w[l][c2][k]; c2>=128 -> output1_w[c2-128][l*128+k]
// ---------------------------------------------------------------------------
__global__ __launch_bounds__(256) void prep_weights(
    const float* __restrict__ conv_w, const float* __restrict__ out_w,
    const float* __restrict__ out1_w, float* __restrict__ wA, float* __restrict__ wB)
{
    int n = blockIdx.x * 256 + threadIdx.x;
    const int NA = NLAYER * 384 * 256;   // 884736
    const int NB = NLAYER * 128 * 256;   // 294912
    if (n < NA) {
        int c = n & 255; int q = n >> 8;
        int kk = q % 384; int l = q / 384;
        int tap = kk >> 7; int r = kk & 127;
        wA[n] = conv_w[((size_t)(l * 256 + c) * 128 + r) * 3 + tap];
    } else if (n < NA + NB) {
        int m = n - NA;
        int c2 = m & 255; int q = m >> 8;
        int k = q & 127; int l = q >> 7;
        float v;
        if (c2 < 128) v = out_w[(size_t)(l * 128 + c2) * 128 + k];
        else          v = out1_w[(size_t)(c2 - 128) * 1152 + l * 128 + k];
        wB[m] = v;
    }
}

// h[b][t][r] = tanh(iw[r]*x[b][t] + ib[r]);  acc1 zero-init
__global__ __launch_bounds__(256) void input_init(
    const float* __restrict__ x, const float* __restrict__ iw,
    const float* __restrict__ ib,
    float* __restrict__ h, float* __restrict__ acc1)
{
    int n = blockIdx.x * 256 + threadIdx.x;   // n < B*T*R
    int r = n & 127; int bt = n >> 7;
    h[n] = fast_tanh(iw[r] * x[bt] + ib[r]);
    acc1[n] = 0.0f;
}

// ---------------------------------------------------------------------------
// One WaveNet layer, fused:
//   pre[t][c]  = conv_b[c] + sum_{tap,r} wA[tap*128+r][c] * h_in[t-(2-tap)d][r]
//   z = tanh(pre[:, :128]) * sigmoid(pre[:, 128:])
//   h_out[t][c]  = h_in[t][c] + out_b[c] + sum_k wB[k][c]     * z[t][k]
//   acc1[t][c]  +=                         sum_k wB[k][c+128] * z[t][k]
// Block: 256 threads, 64 timesteps x 256 channels. Thread tile 8t x 8c.
// ---------------------------------------------------------------------------
__global__ __launch_bounds__(256) void layer_kernel(
    const float* __restrict__ h_in, float* __restrict__ h_out,
    float* __restrict__ acc1,
    const float* __restrict__ wA,   // [384][256] this layer
    const float* __restrict__ wB,   // [128][256] this layer
    const float* __restrict__ cb,   // conv_b [256]
    const float* __restrict__ ob,   // out_b  [128]
    int d)
{
    __shared__ float As[16][68];     // padded: conflict-free + 16B-aligned rows
    __shared__ float Bs[16][256];
    __shared__ float zs[64][128];

    const int b  = blockIdx.y;
    const int t0 = blockIdx.x * 64;
    const int tid = threadIdx.x;
    const int tc = tid & 31;         // channel group: c = 4*tc (+128 pair)
    const int tg = tid >> 5;         // time group:    t = 8*tg + i

    const float* hb = h_in + (size_t)b * (T_LEN * R_CH);

    float acc[8][8];
#pragma unroll
    for (int i = 0; i < 8; ++i)
#pragma unroll
        for (int j = 0; j < 8; ++j) acc[i][j] = 0.0f;

    // ---------------- Phase 1: dilated conv GEMM (K = 384) ----------------
    for (int kc = 0; kc < 384; kc += 16) {
        const int tap = kc >> 7;
        const int rb  = kc & 127;
        const int off = (2 - tap) * d;
        __syncthreads();
        // stage As[kk][m] = h[t0+m-off][rb+kk]  (1024 elems)
#pragma unroll
        for (int i = 0; i < 4; ++i) {
            int e = tid + i * 256;
            int kk = e & 15, m = e >> 4;
            int t = t0 + m - off;
            As[kk][m] = (t >= 0) ? hb[(size_t)t * 128 + rb + kk] : 0.0f;
        }
        // stage Bs (4096 elems, coalesced)
        {
            const float* src = wA + (size_t)kc * 256;
            float* dst = &Bs[0][0];
#pragma unroll
            for (int i = 0; i < 16; ++i) dst[tid + i * 256] = src[tid + i * 256];
        }
        __syncthreads();
#pragma unroll
        for (int kk = 0; kk < 16; ++kk) {
            float4 a0 = *(const float4*)&As[kk][8 * tg];
            float4 a1 = *(const float4*)&As[kk][8 * tg + 4];
            float4 b0 = *(const float4*)&Bs[kk][4 * tc];
            float4 b1 = *(const float4*)&Bs[kk][4 * tc + 128];
            float av[8] = {a0.x, a0.y, a0.z, a0.w, a1.x, a1.y, a1.z, a1.w};
            float bv[8] = {b0.x, b0.y, b0.z, b0.w, b1.x, b1.y, b1.z, b1.w};
#pragma unroll
            for (int i = 0; i < 8; ++i)
#pragma unroll
                for (int j = 0; j < 8; ++j) acc[i][j] += av[i] * bv[j];
        }
    }

    // ---------------- Gating -> z in LDS ----------------
#pragma unroll
    for (int i = 0; i < 8; ++i) {
        float4 zv;
        float* zp = (float*)&zv;
#pragma unroll
        for (int j = 0; j < 4; ++j) {
            float tpre = acc[i][j]     + cb[4 * tc + j];
            float gpre = acc[i][j + 4] + cb[4 * tc + j + 128];
            zp[j] = fast_tanh(tpre) * fast_sigmoid(gpre);
        }
        *(float4*)&zs[8 * tg + i][4 * tc] = zv;
    }

    // ---------------- Phase 2: res + skip GEMMs (K = 128) ----------------
    float accR[8][4], accS[8][4];
#pragma unroll
    for (int i = 0; i < 8; ++i)
#pragma unroll
        for (int j = 0; j < 4; ++j) { accR[i][j] = 0.0f; accS[i][j] = 0.0f; }

    for (int kc = 0; kc < 128; kc += 16) {
        __syncthreads();   // zs visible (first iter); Bs consumed (later iters)
        {
            const float* src = wB + (size_t)kc * 256;
            float* dst = &Bs[0][0];
#pragma unroll
            for (int i = 0; i < 16; ++i) dst[tid + i * 256] = src[tid + i * 256];
        }
        __syncthreads();
#pragma unroll
        for (int kk = 0; kk < 16; ++kk) {
            float4 b0 = *(const float4*)&Bs[kk][4 * tc];         // res weights
            float4 b1 = *(const float4*)&Bs[kk][4 * tc + 128];   // skip weights
#pragma unroll
            for (int i = 0; i < 8; ++i) {
                float a = zs[8 * tg + i][kc + kk];
                accR[i][0] += a * b0.x; accR[i][1] += a * b0.y;
                accR[i][2] += a * b0.z; accR[i][3] += a * b0.w;
                accS[i][0] += a * b1.x; accS[i][1] += a * b1.y;
                accS[i][2] += a * b1.z; accS[i][3] += a * b1.w;
            }
        }
    }

    // ---------------- Epilogue: h_out = h_in + res + ob;  acc1 += skip ------
    float ob0 = ob[4 * tc + 0], ob1 = ob[4 * tc + 1];
    float ob2 = ob[4 * tc + 2], ob3 = ob[4 * tc + 3];
#pragma unroll
    for (int i = 0; i < 8; ++i) {
        size_t t = t0 + 8 * tg + i;
        size_t base = ((size_t)b * T_LEN + t) * 128 + 4 * tc;
        float4 hin = *(const float4*)&hb[t * 128 + 4 * tc];
        float4 ho;
        ho.x = hin.x + accR[i][0] + ob0;
        ho.y = hin.y + accR[i][1] + ob1;
        ho.z = hin.z + accR[i][2] + ob2;
        ho.w = hin.w + accR[i][3] + ob3;
        *(float4*)&h_out[base] = ho;
        float4 av = *(const float4*)&acc1[base];
        av.x += accS[i][0]; av.y += accS[i][1];
        av.z += accS[i][2]; av.w += accS[i][3];
        *(float4*)&acc1[base] = av;
    }
}

// out[bt] = o2b + sum_r o2w[r] * tanh(acc1[bt][r] + o1b[r]); one wave per bt
__global__ __launch_bounds__(256) void final_kernel(
    const float* __restrict__ acc1, const float* __restrict__ b1,
    const float* __restrict__ w2, const float* __restrict__ b2,
    float* __restrict__ out)
{
    int lane = threadIdx.x & 63;
    int w = threadIdx.x >> 6;
    int bt = blockIdx.x * 4 + w;
    int r0 = lane, r1 = lane + 64;
    float v0 = acc1[(size_t)bt * 128 + r0];
    float v1 = acc1[(size_t)bt * 128 + r1];
    float s = w2[r0] * fast_tanh(v0 + b1[r0]) + w2[r1] * fast_tanh(v1 + b1[r1]);
#pragma unroll
    for (int k = 1; k < 64; k <<= 1) s += __shfl_xor(s, k, 64);
    if (lane == 0) out[bt] = s + b2[0];
}

extern "C" void kernel_launch(void* const* d_in, const int* in_sizes, int n_in,
                              void* d_out, int out_size, void* d_ws, size_t ws_size,
                              hipStream_t stream)
{
    const float* x   = (const float*)d_in[0];
    const float* iw  = (const float*)d_in[1];
    const float* ib  = (const float*)d_in[2];
    const float* cw  = (const float*)d_in[3];
    const float* cb  = (const float*)d_in[4];
    const float* ow  = (const float*)d_in[5];
    const float* ob  = (const float*)d_in[6];
    const float* o1w = (const float*)d_in[7];
    const float* o1b = (const float*)d_in[8];
    const float* o2w = (const float*)d_in[9];
    const float* o2b = (const float*)d_in[10];
    float* out = (float*)d_out;

    float* ws = (float*)d_ws;
    const size_t HTR = (size_t)BATCH * T_LEN * R_CH;   // 16777216
    float* hA   = ws;
    float* hB   = hA + HTR;
    float* acc1 = hB + HTR;
    float* wA   = acc1 + HTR;
    float* wB   = wA + (size_t)NLAYER * 384 * 256;
    // total: 3*16777216 + 884736 + 294912 floats ~= 206 MB of ws

    prep_weights<<<4608, 256, 0, stream>>>(cw, ow, o1w, wA, wB);
    input_init<<<65536, 256, 0, stream>>>(x, iw, ib, hA, acc1);

    const int DIL[NLAYER] = {1, 2, 4, 8, 16, 32, 64, 128, 256};
    float* hin = hA; float* hout = hB;
    for (int l = 0; l < NLAYER; ++l) {
        layer_kernel<<<dim3(T_LEN / 64, BATCH), 256, 0, stream>>>(
            hin, hout, acc1,
            wA + (size_t)l * 384 * 256, wB + (size_t)l * 128 * 256,
            cb + l * 256, ob + l * 128, DIL[l]);
        float* tmp = hin; hin = hout; hout = tmp;
    }
    final_kernel<<<BATCH * T_LEN / 4, 256, 0, stream>>>(acc1, o1b, o2w, o2b, out);
}

// Round 2
// 3173.970 us; speedup vs baseline: 2.0482x; 2.0482x over previous
//
#include <hip/hip_runtime.h>
#include <cstdint>
#include <cstddef>

#define T_LEN 16384
#define R_CH  128
#define BATCH 8
#define NLAYER 9

typedef __attribute__((ext_vector_type(8))) short bf16x8;
typedef __attribute__((ext_vector_type(4))) float f32x4;
#define MFMA_BF16 __builtin_amdgcn_mfma_f32_16x16x32_bf16

__device__ __forceinline__ float fast_sigmoid(float x) {
    return 1.0f / (1.0f + __expf(-x));
}
__device__ __forceinline__ float fast_tanh(float x) {
    return 1.0f - 2.0f / (__expf(2.0f * x) + 1.0f);
}
__device__ __forceinline__ short f2bf(float f) {
    union { float f; unsigned u; } v; v.f = f;
    unsigned r = (v.u + 0x7FFF + ((v.u >> 16) & 1)) >> 16;
    return (short)r;
}

// ---------------------------------------------------------------------------
// Weight prepack to bf16 in B-fragment-friendly order:
//  wAp[l][chunk12][n256][k'32] = conv_w[l][n][r][tap], k=chunk*32+k', tap=k>>7, r=k&127
//  wBp[l][chunk4][n256][k'32]: n<128 -> out_w[l][n][k]; n>=128 -> output1_w[n-128][l*128+k]
// ---------------------------------------------------------------------------
__global__ __launch_bounds__(256) void prep_weights(
    const float* __restrict__ cw, const float* __restrict__ ow,
    const float* __restrict__ o1w, short* __restrict__ wAp, short* __restrict__ wBp)
{
    int n = blockIdx.x * 256 + threadIdx.x;
    const int NA = NLAYER * 12 * 256 * 32;   // 884736
    const int NB = NLAYER * 4 * 256 * 32;    // 294912
    if (n < NA) {
        int kp = n & 31; int q = n >> 5;
        int c = q & 255; q >>= 8;
        int chunk = q % 12; int l = q / 12;
        int k = chunk * 32 + kp;
        int tap = k >> 7, r = k & 127;
        wAp[n] = f2bf(cw[((size_t)(l * 256 + c) * 128 + r) * 3 + tap]);
    } else if (n < NA + NB) {
        int m = n - NA;
        int kp = m & 31; int q = m >> 5;
        int c = q & 255; q >>= 8;
        int chunk = q & 3; int l = q >> 2;
        int k = chunk * 32 + kp;
        float v = (c < 128) ? ow[(size_t)(l * 128 + c) * 128 + k]
                            : o1w[(size_t)(c - 128) * 1152 + l * 128 + k];
        wBp[m] = f2bf(v);
    }
}

// h[b][t][r] = tanh(iw[r]*x[b][t] + ib[r]);  acc1 zero-init
__global__ __launch_bounds__(256) void input_init(
    const float* __restrict__ x, const float* __restrict__ iw,
    const float* __restrict__ ib,
    float* __restrict__ h, float* __restrict__ acc1)
{
    int n = blockIdx.x * 256 + threadIdx.x;
    int r = n & 127; int bt = n >> 7;
    h[n] = fast_tanh(iw[r] * x[bt] + ib[r]);
    acc1[n] = 0.0f;
}

// ---------------------------------------------------------------------------
// One WaveNet layer, MFMA bf16. Block: 256 thr = 4 waves, tile M=128 t x N=256.
// Waves split M (32 rows each) -> As and zs are wave-private -> NO barriers.
// Phase 1: pre = h*WA (K=384, 12 chunks of 32)
// gating -> z (bf16, LDS)
// Phase 2: [res|skip] = z*WB (K=128, 4 chunks)
// Epilogue: h_out = h_in + res + ob;  acc1 += skip
// ---------------------------------------------------------------------------
__global__ __launch_bounds__(256, 3) void layer_kernel(
    const float* __restrict__ h_in, float* __restrict__ h_out,
    float* __restrict__ accG,
    const short* __restrict__ wA,   // [12][256][32] this layer
    const short* __restrict__ wB,   // [4][256][32]  this layer
    const float* __restrict__ cb,   // conv_b [256]
    const float* __restrict__ ob,   // out_b  [128]
    int d)
{
    __shared__ __align__(16) short As[128][40];    // 10 KB, stride 80B (16B-aligned rows)
    __shared__ __align__(16) short zs[128][136];   // 34 KB, stride 272B (16B-aligned rows)

    const int tid  = threadIdx.x;
    const int w    = tid >> 6;
    const int lane = tid & 63;
    const int col  = lane & 15;
    const int quad = lane >> 4;
    const int b    = blockIdx.y;
    const int t0   = blockIdx.x * 128;

    const float* hb = h_in + (size_t)b * (T_LEN * R_CH);

    // A staging: thread owns row sm = tid>>1 (== its own wave's 32 rows),
    // half sq = tid&1 (16 k-values)
    const int sm = tid >> 1;
    const int sq = tid & 1;

    const int rowA0 = w * 32 + col;       // m-tile 0 row for frag reads
    const int rowA1 = rowA0 + 16;         // m-tile 1

    // per-lane biases
    float cbf[8], cbg[8], obv[8];
#pragma unroll
    for (int nt = 0; nt < 8; ++nt) {
        cbf[nt] = cb[nt * 16 + col];
        cbg[nt] = cb[128 + nt * 16 + col];
        obv[nt] = ob[nt * 16 + col];
    }

    f32x4 accP[2][16];
#pragma unroll
    for (int mt = 0; mt < 2; ++mt)
#pragma unroll
        for (int nt = 0; nt < 16; ++nt) accP[mt][nt] = (f32x4)0.0f;

    // ---------------- Phase 1: K=384 over 12 chunks ----------------
    float4 pre4[4];
    {
        // prologue: load chunk 0 (tap 0, off = 2d)
        int t = t0 + sm - 2 * d;
        int rb = sq * 16;
        if (t >= 0) {
            const float4* p = (const float4*)(hb + (size_t)t * 128 + rb);
            pre4[0] = p[0]; pre4[1] = p[1]; pre4[2] = p[2]; pre4[3] = p[3];
        } else {
            pre4[0] = pre4[1] = pre4[2] = pre4[3] = make_float4(0.f, 0.f, 0.f, 0.f);
        }
    }

#pragma unroll
    for (int ch = 0; ch < 12; ++ch) {
        // write staged regs -> As (wave-private rows; compiler-inserted lgkmcnt)
        {
            bf16x8 v0, v1;
            const float* pv = (const float*)&pre4[0];
#pragma unroll
            for (int i = 0; i < 8; ++i) { v0[i] = f2bf(pv[i]); v1[i] = f2bf(pv[i + 8]); }
            *(bf16x8*)&As[sm][sq * 16]     = v0;
            *(bf16x8*)&As[sm][sq * 16 + 8] = v1;
        }
        // prefetch next chunk's A from global
        if (ch < 11) {
            int nc  = ch + 1;
            int tap = nc >> 2;
            int t   = t0 + sm - (2 - tap) * d;
            int rb  = (nc & 3) * 32 + sq * 16;
            if (t >= 0) {
                const float4* p = (const float4*)(hb + (size_t)t * 128 + rb);
                pre4[0] = p[0]; pre4[1] = p[1]; pre4[2] = p[2]; pre4[3] = p[3];
            } else {
                pre4[0] = pre4[1] = pre4[2] = pre4[3] = make_float4(0.f, 0.f, 0.f, 0.f);
            }
        }
        // compute chunk ch
        bf16x8 a0 = *(const bf16x8*)&As[rowA0][quad * 8];
        bf16x8 a1 = *(const bf16x8*)&As[rowA1][quad * 8];
        const short* wAc = wA + ch * (256 * 32);
#pragma unroll
        for (int nt = 0; nt < 16; ++nt) {
            bf16x8 bf = *(const bf16x8*)&wAc[(nt * 16 + col) * 32 + quad * 8];
            accP[0][nt] = MFMA_BF16(a0, bf, accP[0][nt], 0, 0, 0);
            accP[1][nt] = MFMA_BF16(a1, bf, accP[1][nt], 0, 0, 0);
        }
    }

    // ---------------- Gating -> zs (wave-private rows) ----------------
#pragma unroll
    for (int mt = 0; mt < 2; ++mt)
#pragma unroll
        for (int nt = 0; nt < 8; ++nt)
#pragma unroll
            for (int reg = 0; reg < 4; ++reg) {
                float f = accP[mt][nt][reg]     + cbf[nt];
                float g = accP[mt][nt + 8][reg] + cbg[nt];
                zs[w * 32 + mt * 16 + quad * 4 + reg][nt * 16 + col] =
                    f2bf(fast_tanh(f) * fast_sigmoid(g));
            }

    // ---------------- Phase 2: K=128 over 4 chunks ----------------
#pragma unroll
    for (int mt = 0; mt < 2; ++mt)
#pragma unroll
        for (int nt = 0; nt < 16; ++nt) accP[mt][nt] = (f32x4)0.0f;

#pragma unroll
    for (int ch = 0; ch < 4; ++ch) {
        bf16x8 a0 = *(const bf16x8*)&zs[rowA0][ch * 32 + quad * 8];
        bf16x8 a1 = *(const bf16x8*)&zs[rowA1][ch * 32 + quad * 8];
        const short* wBc = wB + ch * (256 * 32);
#pragma unroll
        for (int nt = 0; nt < 16; ++nt) {
            bf16x8 bf = *(const bf16x8*)&wBc[(nt * 16 + col) * 32 + quad * 8];
            accP[0][nt] = MFMA_BF16(a0, bf, accP[0][nt], 0, 0, 0);
            accP[1][nt] = MFMA_BF16(a1, bf, accP[1][nt], 0, 0, 0);
        }
    }

    // ---------------- Epilogue ----------------
    float* accB = accG + (size_t)b * (T_LEN * R_CH);
    float* hob  = h_out + (size_t)b * (T_LEN * R_CH);
#pragma unroll
    for (int mt = 0; mt < 2; ++mt) {
        int tb = t0 + w * 32 + mt * 16 + quad * 4;
#pragma unroll
        for (int reg = 0; reg < 4; ++reg) {
            size_t rowb = (size_t)(tb + reg) * 128;
#pragma unroll
            for (int nt = 0; nt < 8; ++nt) {
                int c = nt * 16 + col;
                hob[rowb + c]  = hb[rowb + c] + accP[mt][nt][reg] + obv[nt];
                accB[rowb + c] += accP[mt][nt + 8][reg];
            }
        }
    }
}

// out[bt] = o2b + sum_r o2w[r] * tanh(acc1[bt][r] + o1b[r]); one wave per bt
__global__ __launch_bounds__(256) void final_kernel(
    const float* __restrict__ acc1, const float* __restrict__ b1,
    const float* __restrict__ w2, const float* __restrict__ b2,
    float* __restrict__ out)
{
    int lane = threadIdx.x & 63;
    int w = threadIdx.x >> 6;
    int bt = blockIdx.x * 4 + w;
    int r0 = lane, r1 = lane + 64;
    float v0 = acc1[(size_t)bt * 128 + r0];
    float v1 = acc1[(size_t)bt * 128 + r1];
    float s = w2[r0] * fast_tanh(v0 + b1[r0]) + w2[r1] * fast_tanh(v1 + b1[r1]);
#pragma unroll
    for (int k = 1; k < 64; k <<= 1) s += __shfl_xor(s, k, 64);
    if (lane == 0) out[bt] = s + b2[0];
}

extern "C" void kernel_launch(void* const* d_in, const int* in_sizes, int n_in,
                              void* d_out, int out_size, void* d_ws, size_t ws_size,
                              hipStream_t stream)
{
    const float* x   = (const float*)d_in[0];
    const float* iw  = (const float*)d_in[1];
    const float* ib  = (const float*)d_in[2];
    const float* cw  = (const float*)d_in[3];
    const float* cb  = (const float*)d_in[4];
    const float* ow  = (const float*)d_in[5];
    const float* ob  = (const float*)d_in[6];
    const float* o1w = (const float*)d_in[7];
    const float* o1b = (const float*)d_in[8];
    const float* o2w = (const float*)d_in[9];
    const float* o2b = (const float*)d_in[10];
    float* out = (float*)d_out;

    float* ws = (float*)d_ws;
    const size_t HTR = (size_t)BATCH * T_LEN * R_CH;   // 16777216
    float* hA   = ws;
    float* hB   = hA + HTR;
    float* acc1 = hB + HTR;
    short* wAp  = (short*)(acc1 + HTR);
    short* wBp  = wAp + (size_t)NLAYER * 12 * 256 * 32;
    // total: 3*64MB fp32 + ~2.4MB bf16 weights ~= 204 MB of ws

    prep_weights<<<4608, 256, 0, stream>>>(cw, ow, o1w, wAp, wBp);
    input_init<<<65536, 256, 0, stream>>>(x, iw, ib, hA, acc1);

    const int DIL[NLAYER] = {1, 2, 4, 8, 16, 32, 64, 128, 256};
    float* hin = hA; float* hout = hB;
    for (int l = 0; l < NLAYER; ++l) {
        layer_kernel<<<dim3(T_LEN / 128, BATCH), 256, 0, stream>>>(
            hin, hout, acc1,
            wAp + (size_t)l * 12 * 256 * 32, wBp + (size_t)l * 4 * 256 * 32,
            cb + l * 256, ob + l * 128, DIL[l]);
        float* tmp = hin; hin = hout; hout = tmp;
    }
    final_kernel<<<BATCH * T_LEN / 4, 256, 0, stream>>>(acc1, o1b, o2w, o2b, out);
}

// Round 3
// 1745.253 us; speedup vs baseline: 3.7249x; 1.8186x over previous
//
#include <hip/hip_runtime.h>
#include <cstdint>
#include <cstddef>

#define T_LEN 16384
#define BATCH 8
#define NLAYER 9

typedef _Float16 f16;
typedef __attribute__((ext_vector_type(8))) _Float16 f16x8;
typedef __attribute__((ext_vector_type(4))) float f32x4;
#define MFMA_F16 __builtin_amdgcn_mfma_f32_16x16x32_f16

__device__ __forceinline__ float fast_sigmoid(float x) {
    return 1.0f / (1.0f + __expf(-x));
}
__device__ __forceinline__ float fast_tanh(float x) {
    return 1.0f - 2.0f / (__expf(2.0f * x) + 1.0f);
}

// ---------------------------------------------------------------------------
// Weight prepack to fp16, B-fragment order [n][k32-chunk]:
//  wA[l][ch12][n256][kp32] = conv_w[l][n][r][tap], k=ch*32+kp, tap=k>>7, r=k&127
//  wB[l][ch4][n256][kp32]: n<128 -> out_w[l][n][k]; n>=128 -> output1_w[n-128][l*128+k]
// ---------------------------------------------------------------------------
__global__ __launch_bounds__(256) void prep_weights(
    const float* __restrict__ cw, const float* __restrict__ ow,
    const float* __restrict__ o1w, f16* __restrict__ wA, f16* __restrict__ wB)
{
    int n = blockIdx.x * 256 + threadIdx.x;
    const int NA = NLAYER * 12 * 256 * 32;   // 884736
    const int NB = NLAYER * 4 * 256 * 32;    // 294912
    if (n < NA) {
        int kp = n & 31; int q = n >> 5;
        int c = q & 255; q >>= 8;
        int ch = q % 12; int l = q / 12;
        int k = ch * 32 + kp;
        int tap = k >> 7, r = k & 127;
        wA[n] = (f16)cw[((size_t)(l * 256 + c) * 128 + r) * 3 + tap];
    } else if (n < NA + NB) {
        int m = n - NA;
        int kp = m & 31; int q = m >> 5;
        int c = q & 255; q >>= 8;
        int ch = q & 3; int l = q >> 2;
        int k = ch * 32 + kp;
        float v = (c < 128) ? ow[(size_t)(l * 128 + c) * 128 + k]
                            : o1w[(size_t)(c - 128) * 1152 + l * 128 + k];
        wB[m] = (f16)v;
    }
}

// h[b][t][r] = tanh(iw[r]*x[b][t] + ib[r]) (fp16);  acc1 zero-init (fp16)
__global__ __launch_bounds__(256) void input_init(
    const float* __restrict__ x, const float* __restrict__ iw,
    const float* __restrict__ ib,
    f16* __restrict__ h, f16* __restrict__ acc1)
{
    int n = blockIdx.x * 256 + threadIdx.x;
    int r = n & 127; int bt = n >> 7;
    h[n] = (f16)fast_tanh(iw[r] * x[bt] + ib[r]);
    acc1[n] = (f16)0.0f;
}

// ---------------------------------------------------------------------------
// One layer. Block 256 = 4 waves; wave tile M=16 t x N=256. Block M=64.
// A-fragments loaded DIRECTLY from global fp16 h (A[m=col][k=quad*8+:8] is
// 16 contiguous bytes). B-fragments direct from prepacked global weights
// (L1-resident). Wave-private LDS only for the z / epilogue transposes.
// No __syncthreads anywhere.
// ---------------------------------------------------------------------------
__global__ __launch_bounds__(256, 4) void layer_kernel(
    const f16* __restrict__ h_in, f16* __restrict__ h_out,
    f16* __restrict__ acc1,
    const f16* __restrict__ wA,   // [12][256][32] this layer
    const f16* __restrict__ wB,   // [4][256][32]  this layer
    const float* __restrict__ cb, // conv_b [256]
    const float* __restrict__ ob, // out_b  [128]
    int d)
{
    __shared__ __align__(16) f16 zs[4][16][136];   // wave-private, 17.4 KB

    const int tid  = threadIdx.x;
    const int w    = tid >> 6;
    const int lane = tid & 63;
    const int col  = lane & 15;
    const int quad = lane >> 4;
    const int b    = blockIdx.y;
    const int t0   = blockIdx.x * 64;

    const f16* hb = h_in + (size_t)b * T_LEN * 128;
    const int trow = t0 + w * 16 + col;

    f32x4 acc[16];
#pragma unroll
    for (int nt = 0; nt < 16; ++nt) acc[nt] = (f32x4)0.0f;

    // ---------------- Phase 1: pre = h * WA, K=384 (12 chunks) ----------------
#pragma unroll
    for (int ch = 0; ch < 12; ++ch) {
        const int tap = ch >> 2;
        const int t   = trow - (2 - tap) * d;
        const int kb  = (ch & 3) * 32 + quad * 8;
        f16x8 a;
        if (t >= 0) a = *(const f16x8*)&hb[(size_t)t * 128 + kb];
        else        a = (f16x8)(f16)0.0f;
        const f16* wc = wA + ch * (256 * 32);
#pragma unroll
        for (int nt = 0; nt < 16; ++nt) {
            f16x8 bb = *(const f16x8*)&wc[(nt * 16 + col) * 32 + quad * 8];
            acc[nt] = MFMA_F16(a, bb, acc[nt], 0, 0, 0);
        }
    }

    // ---------------- Gating -> z (wave-private LDS transpose) ----------------
    f16* zw = &zs[w][0][0];
#pragma unroll
    for (int nt = 0; nt < 8; ++nt) {
        float cf = cb[nt * 16 + col];
        float cg = cb[128 + nt * 16 + col];
#pragma unroll
        for (int reg = 0; reg < 4; ++reg) {
            float fpre = acc[nt][reg]     + cf;
            float gpre = acc[nt + 8][reg] + cg;
            zw[(quad * 4 + reg) * 136 + nt * 16 + col] =
                (f16)(fast_tanh(fpre) * fast_sigmoid(gpre));
        }
    }

    // ---------------- Phase 2: [res|skip] = z * WB, K=128 (4 chunks) ----------
    f32x4 acc2[16];
#pragma unroll
    for (int nt = 0; nt < 16; ++nt) acc2[nt] = (f32x4)0.0f;

#pragma unroll
    for (int ch = 0; ch < 4; ++ch) {
        f16x8 a = *(const f16x8*)&zw[col * 136 + ch * 32 + quad * 8];
        const f16* wc = wB + ch * (256 * 32);
#pragma unroll
        for (int nt = 0; nt < 16; ++nt) {
            f16x8 bb = *(const f16x8*)&wc[(nt * 16 + col) * 32 + quad * 8];
            acc2[nt] = MFMA_F16(a, bb, acc2[nt], 0, 0, 0);
        }
    }

    // ---------------- Epilogue 1: h_out = h_in + res + ob (via LDS) -----------
#pragma unroll
    for (int nt = 0; nt < 8; ++nt) {
        float o = ob[nt * 16 + col];
#pragma unroll
        for (int reg = 0; reg < 4; ++reg)
            zw[(quad * 4 + reg) * 136 + nt * 16 + col] = (f16)(acc2[nt][reg] + o);
    }
    const int row = lane >> 2, seg = lane & 3;
    const size_t gb = (size_t)b * T_LEN * 128 +
                      (size_t)(t0 + w * 16 + row) * 128 + seg * 32;
#pragma unroll
    for (int i = 0; i < 4; ++i) {
        f16x8 rv = *(const f16x8*)&zw[row * 136 + seg * 32 + i * 8];
        f16x8 hv = *(const f16x8*)&h_in[gb + i * 8];
        *(f16x8*)&h_out[gb + i * 8] = hv + rv;
    }

    // ---------------- Epilogue 2: acc1 += skip (via LDS) ----------------------
#pragma unroll
    for (int nt = 0; nt < 8; ++nt)
#pragma unroll
        for (int reg = 0; reg < 4; ++reg)
            zw[(quad * 4 + reg) * 136 + nt * 16 + col] = (f16)acc2[nt + 8][reg];
#pragma unroll
    for (int i = 0; i < 4; ++i) {
        f16x8 sv = *(const f16x8*)&zw[row * 136 + seg * 32 + i * 8];
        f16x8 av = *(const f16x8*)&acc1[gb + i * 8];
        *(f16x8*)&acc1[gb + i * 8] = av + sv;
    }
}

// out[bt] = o2b + sum_r o2w[r] * tanh(acc1[bt][r] + o1b[r]); one wave per bt
__global__ __launch_bounds__(256) void final_kernel(
    const f16* __restrict__ acc1, const float* __restrict__ b1,
    const float* __restrict__ w2, const float* __restrict__ b2,
    float* __restrict__ out)
{
    int lane = threadIdx.x & 63;
    int w = threadIdx.x >> 6;
    int bt = blockIdx.x * 4 + w;
    float v0 = (float)acc1[(size_t)bt * 128 + lane];
    float v1 = (float)acc1[(size_t)bt * 128 + lane + 64];
    float s = w2[lane] * fast_tanh(v0 + b1[lane]) +
              w2[lane + 64] * fast_tanh(v1 + b1[lane + 64]);
#pragma unroll
    for (int k = 1; k < 64; k <<= 1) s += __shfl_xor(s, k, 64);
    if (lane == 0) out[bt] = s + b2[0];
}

extern "C" void kernel_launch(void* const* d_in, const int* in_sizes, int n_in,
                              void* d_out, int out_size, void* d_ws, size_t ws_size,
                              hipStream_t stream)
{
    const float* x   = (const float*)d_in[0];
    const float* iw  = (const float*)d_in[1];
    const float* ib  = (const float*)d_in[2];
    const float* cw  = (const float*)d_in[3];
    const float* cb  = (const float*)d_in[4];
    const float* ow  = (const float*)d_in[5];
    const float* ob  = (const float*)d_in[6];
    const float* o1w = (const float*)d_in[7];
    const float* o1b = (const float*)d_in[8];
    const float* o2w = (const float*)d_in[9];
    const float* o2b = (const float*)d_in[10];
    float* out = (float*)d_out;

    const size_t HTR = (size_t)BATCH * T_LEN * 128;   // 16777216
    f16* hA   = (f16*)d_ws;
    f16* hB   = hA + HTR;
    f16* acc1 = hB + HTR;
    f16* wAp  = acc1 + HTR;
    f16* wBp  = wAp + (size_t)NLAYER * 12 * 256 * 32;
    // total ~ 3*32 MB + 2.4 MB = ~103 MB of ws

    prep_weights<<<4608, 256, 0, stream>>>(cw, ow, o1w, wAp, wBp);
    input_init<<<65536, 256, 0, stream>>>(x, iw, ib, hA, acc1);

    const int DIL[NLAYER] = {1, 2, 4, 8, 16, 32, 64, 128, 256};
    f16* hin = hA; f16* hout = hB;
    for (int l = 0; l < NLAYER; ++l) {
        layer_kernel<<<dim3(T_LEN / 64, BATCH), 256, 0, stream>>>(
            hin, hout, acc1,
            wAp + (size_t)l * 12 * 256 * 32, wBp + (size_t)l * 4 * 256 * 32,
            cb + l * 256, ob + l * 128, DIL[l]);
        f16* tmp = hin; hin = hout; hout = tmp;
    }
    final_kernel<<<BATCH * T_LEN / 4, 256, 0, stream>>>(acc1, o1b, o2w, o2b, out);
}

// Round 4
// 870.006 us; speedup vs baseline: 7.4723x; 2.0060x over previous
//
#include <hip/hip_runtime.h>
#include <cstdint>
#include <cstddef>

#define T_LEN 16384
#define BATCH 8
#define NLAYER 9

typedef _Float16 f16;
typedef __attribute__((ext_vector_type(8))) _Float16 f16x8;
typedef __attribute__((ext_vector_type(4))) float f32x4;
#define MFMA_F16 __builtin_amdgcn_mfma_f32_16x16x32_f16

__device__ __forceinline__ float fast_sigmoid(float x) {
    return 1.0f / (1.0f + __expf(-x));
}
__device__ __forceinline__ float fast_tanh(float x) {
    return 1.0f - 2.0f / (__expf(2.0f * x) + 1.0f);
}

// ---------------------------------------------------------------------------
// Weight prepack to fp16, B-fragment order [n][k32-chunk] (same as R3):
//  wA[l][ch12][n256][kp32] = conv_w[l][n][r][tap], k=ch*32+kp... NOTE k here is
//    (tap = ch>>2, r = (ch&3)*32+kp) -> matches phase-1 chunk mapping below.
//  wB[l][ch4][n256][kp32]: n<128 -> out_w[l][n][k]; n>=128 -> output1_w[n-128][l*128+k]
// ---------------------------------------------------------------------------
__global__ __launch_bounds__(256) void prep_weights(
    const float* __restrict__ cw, const float* __restrict__ ow,
    const float* __restrict__ o1w, f16* __restrict__ wA, f16* __restrict__ wB)
{
    int n = blockIdx.x * 256 + threadIdx.x;
    const int NA = NLAYER * 12 * 256 * 32;   // 884736
    const int NB = NLAYER * 4 * 256 * 32;    // 294912
    if (n < NA) {
        int kp = n & 31; int q = n >> 5;
        int c = q & 255; q >>= 8;
        int ch = q % 12; int l = q / 12;
        int tap = ch >> 2;
        int r = (ch & 3) * 32 + kp;
        wA[n] = (f16)cw[((size_t)(l * 256 + c) * 128 + r) * 3 + tap];
    } else if (n < NA + NB) {
        int m = n - NA;
        int kp = m & 31; int q = m >> 5;
        int c = q & 255; q >>= 8;
        int ch = q & 3; int l = q >> 2;
        int k = ch * 32 + kp;
        float v = (c < 128) ? ow[(size_t)(l * 128 + c) * 128 + k]
                            : o1w[(size_t)(c - 128) * 1152 + l * 128 + k];
        wB[m] = (f16)v;
    }
}

// h[b][t][r] = tanh(iw[r]*x[b][t] + ib[r]) (fp16);  acc1 zero-init (fp16)
__global__ __launch_bounds__(256) void input_init(
    const float* __restrict__ x, const float* __restrict__ iw,
    const float* __restrict__ ib,
    f16* __restrict__ h, f16* __restrict__ acc1)
{
    int n = blockIdx.x * 256 + threadIdx.x;
    int r = n & 127; int bt = n >> 7;
    h[n] = (f16)fast_tanh(iw[r] * x[bt] + ib[r]);
    acc1[n] = (f16)0.0f;
}

// ---------------------------------------------------------------------------
// One layer. Block 256 thr = 4 waves: wave (mg, ng); block tile M=64 x N=256.
// Wave tile M=32 (2 m-tiles) x N=128 (8 nt, gate-paired: nt<4 -> filter j,
// nt>=4 -> filter j+128, j = ng*64 + nt*16 + col).
// B staged in LDS (double-buffered, 1 barrier/chunk) shared by all 4 waves.
// A-fragments loaded directly from global fp16 h (16B contiguous, L1-reused
// by the two ng-waves covering the same rows).
// ---------------------------------------------------------------------------
__global__ __launch_bounds__(256, 3) void layer_kernel(
    const f16* __restrict__ h_in, f16* __restrict__ h_out,
    f16* __restrict__ acc1,
    const f16* __restrict__ wA,   // [12][256][32] this layer
    const f16* __restrict__ wB,   // [4][256][32]  this layer
    const float* __restrict__ cb, // conv_b [256]
    const float* __restrict__ ob, // out_b  [128]
    int d)
{
    __shared__ __align__(16) f16 Bs[2][256 * 32];  // 32 KB double buffer
    __shared__ __align__(16) f16 zs[64][136];      // 17.4 KB (z + epilogue xpose)

    const int tid  = threadIdx.x;
    const int lane = tid & 63;
    const int w4   = tid >> 6;
    const int mg   = w4 & 1;          // m-group: rows [mg*32, +32)
    const int ng   = w4 >> 1;         // n-group: filter pairs [ng*64, +64)
    const int col  = lane & 15;
    const int quad = lane >> 4;
    const int b    = blockIdx.y;
    const int t0   = blockIdx.x * 64;

    const f16* hb = h_in + (size_t)b * T_LEN * 128;

    f32x4 acc[2][8];
#pragma unroll
    for (int mt = 0; mt < 2; ++mt)
#pragma unroll
        for (int nt = 0; nt < 8; ++nt) acc[mt][nt] = (f32x4)0.0f;

    // ---------------- Phase 1: pre = h * WA, K=384 (12 chunks of 32) --------
    f16x8 sv[4];
    {
        const f16* src = wA;          // chunk 0
#pragma unroll
        for (int i = 0; i < 4; ++i) sv[i] = *(const f16x8*)&src[tid * 32 + i * 8];
#pragma unroll
        for (int i = 0; i < 4; ++i) *(f16x8*)&Bs[0][tid * 32 + i * 8] = sv[i];
    }
    __syncthreads();

#pragma unroll
    for (int ch = 0; ch < 12; ++ch) {
        // issue next chunk's global loads early
        if (ch < 11) {
            const f16* src = wA + (ch + 1) * (256 * 32);
#pragma unroll
            for (int i = 0; i < 4; ++i) sv[i] = *(const f16x8*)&src[tid * 32 + i * 8];
        }
        // compute chunk ch from Bs[ch&1]
        const int tap = ch >> 2;
        const int off = (2 - tap) * d;
        const int kb  = (ch & 3) * 32 + quad * 8;
        const f16* bsc = &Bs[ch & 1][0];
        f16x8 a[2];
#pragma unroll
        for (int mt = 0; mt < 2; ++mt) {
            int t = t0 + mg * 32 + mt * 16 + col - off;
            if (t >= 0) a[mt] = *(const f16x8*)&hb[(size_t)t * 128 + kb];
            else        a[mt] = (f16x8)(f16)0.0f;
        }
#pragma unroll
        for (int nt = 0; nt < 8; ++nt) {
            int nb = (nt < 4) ? (ng * 64 + nt * 16) : (128 + ng * 64 + (nt - 4) * 16);
            f16x8 bf = *(const f16x8*)&bsc[(nb + col) * 32 + quad * 8];
            acc[0][nt] = MFMA_F16(a[0], bf, acc[0][nt], 0, 0, 0);
            acc[1][nt] = MFMA_F16(a[1], bf, acc[1][nt], 0, 0, 0);
        }
        if (ch < 11) {
#pragma unroll
            for (int i = 0; i < 4; ++i)
                *(f16x8*)&Bs[(ch + 1) & 1][tid * 32 + i * 8] = sv[i];
        }
        __syncthreads();
    }

    // ---------------- Gating -> zs[64][136]; stage wB chunk 0 ---------------
#pragma unroll
    for (int nt = 0; nt < 4; ++nt) {
        int j = ng * 64 + nt * 16 + col;
        float cf = cb[j];
        float cg = cb[j + 128];
#pragma unroll
        for (int mt = 0; mt < 2; ++mt)
#pragma unroll
            for (int reg = 0; reg < 4; ++reg) {
                float f = acc[mt][nt][reg]     + cf;
                float g = acc[mt][nt + 4][reg] + cg;
                zs[mg * 32 + mt * 16 + quad * 4 + reg][j] =
                    (f16)(fast_tanh(f) * fast_sigmoid(g));
            }
    }
    {
        const f16* src = wB;          // chunk 0
#pragma unroll
        for (int i = 0; i < 4; ++i) sv[i] = *(const f16x8*)&src[tid * 32 + i * 8];
#pragma unroll
        for (int i = 0; i < 4; ++i) *(f16x8*)&Bs[0][tid * 32 + i * 8] = sv[i];
    }
    __syncthreads();

    // ---------------- Phase 2: [res|skip] = z * WB, K=128 (4 chunks) --------
    f32x4 acc2[2][8];
#pragma unroll
    for (int mt = 0; mt < 2; ++mt)
#pragma unroll
        for (int nt = 0; nt < 8; ++nt) acc2[mt][nt] = (f32x4)0.0f;

#pragma unroll
    for (int ch = 0; ch < 4; ++ch) {
        if (ch < 3) {
            const f16* src = wB + (ch + 1) * (256 * 32);
#pragma unroll
            for (int i = 0; i < 4; ++i) sv[i] = *(const f16x8*)&src[tid * 32 + i * 8];
        }
        const f16* bsc = &Bs[ch & 1][0];
        f16x8 a[2];
#pragma unroll
        for (int mt = 0; mt < 2; ++mt)
            a[mt] = *(const f16x8*)&zs[mg * 32 + mt * 16 + col][ch * 32 + quad * 8];
#pragma unroll
        for (int nt = 0; nt < 8; ++nt) {
            int nb = (nt < 4) ? (ng * 64 + nt * 16) : (128 + ng * 64 + (nt - 4) * 16);
            f16x8 bf = *(const f16x8*)&bsc[(nb + col) * 32 + quad * 8];
            acc2[0][nt] = MFMA_F16(a[0], bf, acc2[0][nt], 0, 0, 0);
            acc2[1][nt] = MFMA_F16(a[1], bf, acc2[1][nt], 0, 0, 0);
        }
        if (ch < 3) {
#pragma unroll
            for (int i = 0; i < 4; ++i)
                *(f16x8*)&Bs[(ch + 1) & 1][tid * 32 + i * 8] = sv[i];
        }
        __syncthreads();
    }

    // ---------------- Epilogue 1: h_out = h_in + res + ob (via zs xpose) ----
#pragma unroll
    for (int nt = 0; nt < 4; ++nt) {
        int n = ng * 64 + nt * 16 + col;      // res channel
        float o = ob[n];
#pragma unroll
        for (int mt = 0; mt < 2; ++mt)
#pragma unroll
            for (int reg = 0; reg < 4; ++reg)
                zs[mg * 32 + mt * 16 + quad * 4 + reg][n] =
                    (f16)(acc2[mt][nt][reg] + o);
    }
    __syncthreads();
    const int orow = tid >> 2, oseg = tid & 3;
    const size_t gb = (size_t)b * T_LEN * 128 + (size_t)(t0 + orow) * 128 + oseg * 32;
#pragma unroll
    for (int i = 0; i < 4; ++i) {
        f16x8 rv = *(const f16x8*)&zs[orow][oseg * 32 + i * 8];
        f16x8 hv = *(const f16x8*)&h_in[gb + i * 8];
        *(f16x8*)&h_out[gb + i * 8] = hv + rv;
    }
    __syncthreads();

    // ---------------- Epilogue 2: acc1 += skip (via zs xpose) ---------------
#pragma unroll
    for (int nt = 0; nt < 4; ++nt) {
        int n = ng * 64 + nt * 16 + col;      // skip channel
#pragma unroll
        for (int mt = 0; mt < 2; ++mt)
#pragma unroll
            for (int reg = 0; reg < 4; ++reg)
                zs[mg * 32 + mt * 16 + quad * 4 + reg][n] = (f16)acc2[mt][nt + 4][reg];
    }
    __syncthreads();
#pragma unroll
    for (int i = 0; i < 4; ++i) {
        f16x8 sv2 = *(const f16x8*)&zs[orow][oseg * 32 + i * 8];
        f16x8 av  = *(const f16x8*)&acc1[gb + i * 8];
        *(f16x8*)&acc1[gb + i * 8] = av + sv2;
    }
}

// out[bt] = o2b + sum_r o2w[r] * tanh(acc1[bt][r] + o1b[r]); one wave per bt
__global__ __launch_bounds__(256) void final_kernel(
    const f16* __restrict__ acc1, const float* __restrict__ b1,
    const float* __restrict__ w2, const float* __restrict__ b2,
    float* __restrict__ out)
{
    int lane = threadIdx.x & 63;
    int w = threadIdx.x >> 6;
    int bt = blockIdx.x * 4 + w;
    float v0 = (float)acc1[(size_t)bt * 128 + lane];
    float v1 = (float)acc1[(size_t)bt * 128 + lane + 64];
    float s = w2[lane] * fast_tanh(v0 + b1[lane]) +
              w2[lane + 64] * fast_tanh(v1 + b1[lane + 64]);
#pragma unroll
    for (int k = 1; k < 64; k <<= 1) s += __shfl_xor(s, k, 64);
    if (lane == 0) out[bt] = s + b2[0];
}

extern "C" void kernel_launch(void* const* d_in, const int* in_sizes, int n_in,
                              void* d_out, int out_size, void* d_ws, size_t ws_size,
                              hipStream_t stream)
{
    const float* x   = (const float*)d_in[0];
    const float* iw  = (const float*)d_in[1];
    const float* ib  = (const float*)d_in[2];
    const float* cw  = (const float*)d_in[3];
    const float* cb  = (const float*)d_in[4];
    const float* ow  = (const float*)d_in[5];
    const float* ob  = (const float*)d_in[6];
    const float* o1w = (const float*)d_in[7];
    const float* o1b = (const float*)d_in[8];
    const float* o2w = (const float*)d_in[9];
    const float* o2b = (const float*)d_in[10];
    float* out = (float*)d_out;

    const size_t HTR = (size_t)BATCH * T_LEN * 128;   // 16777216
    f16* hA   = (f16*)d_ws;
    f16* hB   = hA + HTR;
    f16* acc1 = hB + HTR;
    f16* wAp  = acc1 + HTR;
    f16* wBp  = wAp + (size_t)NLAYER * 12 * 256 * 32;
    // total ~ 3*32 MB + 2.4 MB = ~103 MB of ws

    prep_weights<<<4608, 256, 0, stream>>>(cw, ow, o1w, wAp, wBp);
    input_init<<<65536, 256, 0, stream>>>(x, iw, ib, hA, acc1);

    const int DIL[NLAYER] = {1, 2, 4, 8, 16, 32, 64, 128, 256};
    f16* hin = hA; f16* hout = hB;
    for (int l = 0; l < NLAYER; ++l) {
        layer_kernel<<<dim3(T_LEN / 64, BATCH), 256, 0, stream>>>(
            hin, hout, acc1,
            wAp + (size_t)l * 12 * 256 * 32, wBp + (size_t)l * 4 * 256 * 32,
            cb + l * 256, ob + l * 128, DIL[l]);
        f16* tmp = hin; hin = hout; hout = tmp;
    }
    final_kernel<<<BATCH * T_LEN / 4, 256, 0, stream>>>(acc1, o1b, o2w, o2b, out);
}